// Round 5
// baseline (1306.670 us; speedup 1.0000x reference)
//
#include <hip/hip_runtime.h>
#include <math.h>

#define AB 128   // A == B == 128
#define NN 64    // N
#define HD 1024  // H

// ---------------------------------------------------------------------------
// ws layout (floats):
//   [0, 8192)      FYt transposed: FYt[a][n], a in [0,128), n in [0,64)
//   [8192, 16384)  FXt transposed: FXt[b][m], b in [0,128), m in [0,64)
//   [16384]        gamma
// ---------------------------------------------------------------------------

__device__ __forceinline__ float wave_reduce(float v) {
  v += __shfl_down(v, 32);
  v += __shfl_down(v, 16);
  v += __shfl_down(v, 8);
  v += __shfl_down(v, 4);
  v += __shfl_down(v, 2);
  v += __shfl_down(v, 1);
  return v;  // valid in lane 0
}

// 1024 threads, 1 block. Shuffle-based reductions (few barriers).
__global__ __launch_bounds__(1024) void fb_setup(
    const float* __restrict__ h, const float* __restrict__ Ww,
    const float* __restrict__ Wb, float* __restrict__ ws) {
  __shared__ float redp[16][5];   // per-wave partials for params
  __shared__ float reds[16][2];   // per-wave partials for sums
  __shared__ float sc[5];
  __shared__ float ssum[2];
  const int tid = threadIdx.x;
  const int lane = tid & 63;
  const int wv = tid >> 6;  // 16 waves

  // ---- params[j] = dot(h[0,:], W[j,:]) + b[j] ----
  const float hv = h[tid];  // HD == 1024 == blockDim
  float p[5];
#pragma unroll
  for (int j = 0; j < 5; ++j) p[j] = hv * Ww[j * HD + tid];
#pragma unroll
  for (int j = 0; j < 5; ++j) {
    float r = wave_reduce(p[j]);
    if (lane == 0) redp[wv][j] = r;
  }
  __syncthreads();
  if (tid < 5) {
    float s = Wb[tid];
#pragma unroll
    for (int w = 0; w < 16; ++w) s += redp[w][tid];
    sc[tid] = s;
  }
  __syncthreads();

  const float gt_X = sc[0], gt_Y = sc[1], log_var = sc[2], log_dt = sc[3];
  const float var = expf(log_var + 1e-8f);
  const float g_X = (129.0f * (gt_X + 1.0f)) / 2.0f;
  const float g_Y = (129.0f * (gt_Y + 1.0f)) / 2.0f;
  const float d = (expf(log_dt) * 127.0f) / 63.0f;
  const float twovar = 2.0f * var;

  // ---- filterbank values: 8 per thread each, kept in registers ----
  float fyv[8], fxv[8];
  float sY = 0.f, sX = 0.f;
#pragma unroll
  for (int c = 0; c < 8; ++c) {
    const int idx = tid + 1024 * c;
    const int n = idx >> 7;
    const int col = idx & 127;
    const float idxn = (float)n - 32.5f;
    const float muX = g_X + idxn * d;
    const float muY = g_Y + idxn * d;
    const float dx = (float)col - muX;
    const float dy = (float)col - muY;
    const float fx = expf(-(dx * dx) / twovar);
    const float fy = expf(-(dy * dy) / twovar);
    fyv[c] = fy;
    fxv[c] = fx;
    sY += fy;
    sX += fx;
  }
  {
    float rY = wave_reduce(sY);
    float rX = wave_reduce(sX);
    if (lane == 0) { reds[wv][0] = rY; reds[wv][1] = rX; }
  }
  __syncthreads();
  if (tid < 2) {
    float s = 0.f;
#pragma unroll
    for (int w = 0; w < 16; ++w) s += reds[w][tid];
    ssum[tid] = s;
  }
  __syncthreads();
  const float invY = 1.0f / ssum[0];
  const float invX = 1.0f / ssum[1];
#pragma unroll
  for (int c = 0; c < 8; ++c) {
    const int idx = tid + 1024 * c;
    const int n = idx >> 7;
    const int col = idx & 127;
    ws[col * NN + n] = fyv[c] * invY;             // FYt[a=col][n]
    ws[8192 + col * NN + n] = fxv[c] * invX;      // FXt[b=col][m]
  }
  if (tid == 0) ws[16384] = expf(sc[4]);
}

// ---------------------------------------------------------------------------
// 2048 blocks x 256 threads (4 waves) = exactly 8 blocks/CU, no tail.
// Block = one image. Wave w owns out rows 16w..16w+15 end-to-end (out row n
// depends only on T row n -> no cross-wave T sharing).
// b-dim chunked 2 x 64: per chunk, wave computes its 16x64 T-chunk into a
// WAVE-PRIVATE 4 KB LDS region (block total 16 KB), then consumes it.
// Stage 1: lane owns one column (coalesced dword Z loads, 16 FMA/load reuse);
//          FY rows via scalar s_load (wave-uniform transposed layout).
// Stage 2: lane = m; T rows read lane-uniform (LDS broadcast, conflict-free);
//          FX coalesced from ws (L1-hot). oacc[16] persists across chunks.
// No launch_bounds min-waves (R3/R4 showed it collapses VGPRs); natural
// pressure ~60 VGPR -> 8 waves/SIMD; LDS 16 KB -> not the limiter.
// ---------------------------------------------------------------------------
__global__ __launch_bounds__(256) void fb_filt(
    const float* __restrict__ x, const float* __restrict__ xh,
    const float* __restrict__ ws, float* __restrict__ out) {
  __shared__ __align__(16) float T[4 * 16 * 64];  // 16 KB, 4 KB per wave

  const int tid = threadIdx.x;
  const int lane = tid & 63;
  const int wv = tid >> 6;
  const int rw16 = __builtin_amdgcn_readfirstlane(wv << 4);  // 16*wave, SGPR
  const int img = blockIdx.x;
  const int k = img >> 1;
  const int which = img & 1;
  const float* __restrict__ Z = (which ? xh : x) + (size_t)k * (AB * AB);
  const float* __restrict__ FYt = ws;
  const float* __restrict__ FXt = ws + NN * AB;
  const float gamma = ws[2 * NN * AB];
  float* __restrict__ Tw = &T[(rw16 << 6)];  // wave-private 16x64 region

  float oacc[16];
#pragma unroll
  for (int j = 0; j < 16; ++j) oacc[j] = 0.f;

#pragma unroll
  for (int c = 0; c < 2; ++c) {
    const int B0 = c << 6;

    // ---- Stage 1: Tchunk[j][lane] = sum_a FYt[a][rw16+j] * Z[a][B0+lane] ----
    float a1[16];
#pragma unroll
    for (int j = 0; j < 16; ++j) a1[j] = 0.f;

    const float* __restrict__ Zc = Z + B0 + lane;
#pragma unroll 4
    for (int a = 0; a < AB; ++a) {
      const float z = Zc[a << 7];                            // coalesced dword
      const float* __restrict__ fyr = FYt + (a << 6) + rw16; // uniform -> s_load
#pragma unroll
      for (int j = 0; j < 16; ++j) a1[j] = fmaf(fyr[j], z, a1[j]);
    }
#pragma unroll
    for (int j = 0; j < 16; ++j) Tw[(j << 6) + lane] = a1[j];  // conflict-free

    __syncthreads();

    // ---- Stage 2: oacc[j] += sum_bb Tchunk[j][bb] * FXt[B0+bb][lane] ----
#pragma unroll
    for (int bb0 = 0; bb0 < 64; bb0 += 16) {
      float fx[16];
#pragma unroll
      for (int i = 0; i < 16; ++i)
        fx[i] = FXt[((B0 + bb0 + i) << 6) + lane];  // coalesced, L1-hot
#pragma unroll
      for (int j = 0; j < 16; ++j) {
        const float* __restrict__ tr = &Tw[(j << 6) + bb0];
        const float4 t0 = *(const float4*)(tr + 0);   // uniform -> broadcast
        const float4 t1 = *(const float4*)(tr + 4);
        const float4 t2 = *(const float4*)(tr + 8);
        const float4 t3 = *(const float4*)(tr + 12);
        float s = oacc[j];
        s = fmaf(t0.x, fx[0], s);
        s = fmaf(t0.y, fx[1], s);
        s = fmaf(t0.z, fx[2], s);
        s = fmaf(t0.w, fx[3], s);
        s = fmaf(t1.x, fx[4], s);
        s = fmaf(t1.y, fx[5], s);
        s = fmaf(t1.z, fx[6], s);
        s = fmaf(t1.w, fx[7], s);
        s = fmaf(t2.x, fx[8], s);
        s = fmaf(t2.y, fx[9], s);
        s = fmaf(t2.z, fx[10], s);
        s = fmaf(t2.w, fx[11], s);
        s = fmaf(t3.x, fx[12], s);
        s = fmaf(t3.y, fx[13], s);
        s = fmaf(t3.z, fx[14], s);
        s = fmaf(t3.w, fx[15], s);
        oacc[j] = s;
      }
    }

    __syncthreads();  // before next chunk overwrites Tchunk
  }

  // ---- Epilogue: out[rw16+j][lane], coalesced dword stores ----
  float* obase = out + (size_t)k * 8192 + which * 4096 + rw16 * NN + lane;
#pragma unroll
  for (int j = 0; j < 16; ++j) {
    obase[j * NN] = gamma * oacc[j];
  }
}

extern "C" void kernel_launch(void* const* d_in, const int* in_sizes, int n_in,
                              void* d_out, int out_size, void* d_ws, size_t ws_size,
                              hipStream_t stream) {
  const float* x = (const float*)d_in[0];
  const float* xh = (const float*)d_in[1];
  const float* h = (const float*)d_in[2];
  const float* Ww = (const float*)d_in[3];
  const float* Wb = (const float*)d_in[4];
  float* ws = (float*)d_ws;
  float* outp = (float*)d_out;

  fb_setup<<<1, 1024, 0, stream>>>(h, Ww, Wb, ws);
  fb_filt<<<2048, 256, 0, stream>>>(x, xh, ws, outp);
}

// Round 6
// 248.964 us; speedup vs baseline: 5.2484x; 5.2484x over previous
//
#include <hip/hip_runtime.h>
#include <math.h>

#define AB 128      // A == B == 128
#define NN 64       // N
#define HD 1024     // H
#define TST 66      // T row stride (64 + 2 pad): all DS access 2-way = free

// ---------------------------------------------------------------------------
// ws layout (floats):
//   [0, 8192)      FYt transposed: FYt[a][n], a in [0,128), n in [0,64)
//   [8192, 16384)  FXt transposed: FXt[b][m], b in [0,128), m in [0,64)
//   [16384]        gamma
// ---------------------------------------------------------------------------

__device__ __forceinline__ float wave_reduce(float v) {
  v += __shfl_down(v, 32);
  v += __shfl_down(v, 16);
  v += __shfl_down(v, 8);
  v += __shfl_down(v, 4);
  v += __shfl_down(v, 2);
  v += __shfl_down(v, 1);
  return v;  // valid in lane 0
}

// 1024 threads, 1 block. Shuffle-based reductions (few barriers).
__global__ __launch_bounds__(1024) void fb_setup(
    const float* __restrict__ h, const float* __restrict__ Ww,
    const float* __restrict__ Wb, float* __restrict__ ws) {
  __shared__ float redp[16][5];   // per-wave partials for params
  __shared__ float reds[16][2];   // per-wave partials for sums
  __shared__ float sc[5];
  __shared__ float ssum[2];
  const int tid = threadIdx.x;
  const int lane = tid & 63;
  const int wv = tid >> 6;  // 16 waves

  // ---- params[j] = dot(h[0,:], W[j,:]) + b[j] ----
  const float hv = h[tid];  // HD == 1024 == blockDim
  float p[5];
#pragma unroll
  for (int j = 0; j < 5; ++j) p[j] = hv * Ww[j * HD + tid];
#pragma unroll
  for (int j = 0; j < 5; ++j) {
    float r = wave_reduce(p[j]);
    if (lane == 0) redp[wv][j] = r;
  }
  __syncthreads();
  if (tid < 5) {
    float s = Wb[tid];
#pragma unroll
    for (int w = 0; w < 16; ++w) s += redp[w][tid];
    sc[tid] = s;
  }
  __syncthreads();

  const float gt_X = sc[0], gt_Y = sc[1], log_var = sc[2], log_dt = sc[3];
  const float var = expf(log_var + 1e-8f);
  const float g_X = (129.0f * (gt_X + 1.0f)) / 2.0f;
  const float g_Y = (129.0f * (gt_Y + 1.0f)) / 2.0f;
  const float d = (expf(log_dt) * 127.0f) / 63.0f;
  const float twovar = 2.0f * var;

  // ---- filterbank values: 8 per thread each, kept in registers ----
  float fyv[8], fxv[8];
  float sY = 0.f, sX = 0.f;
#pragma unroll
  for (int c = 0; c < 8; ++c) {
    const int idx = tid + 1024 * c;
    const int n = idx >> 7;
    const int col = idx & 127;
    const float idxn = (float)n - 32.5f;
    const float muX = g_X + idxn * d;
    const float muY = g_Y + idxn * d;
    const float dx = (float)col - muX;
    const float dy = (float)col - muY;
    const float fx = expf(-(dx * dx) / twovar);
    const float fy = expf(-(dy * dy) / twovar);
    fyv[c] = fy;
    fxv[c] = fx;
    sY += fy;
    sX += fx;
  }
  {
    float rY = wave_reduce(sY);
    float rX = wave_reduce(sX);
    if (lane == 0) { reds[wv][0] = rY; reds[wv][1] = rX; }
  }
  __syncthreads();
  if (tid < 2) {
    float s = 0.f;
#pragma unroll
    for (int w = 0; w < 16; ++w) s += reds[w][tid];
    ssum[tid] = s;
  }
  __syncthreads();
  const float invY = 1.0f / ssum[0];
  const float invX = 1.0f / ssum[1];
#pragma unroll
  for (int c = 0; c < 8; ++c) {
    const int idx = tid + 1024 * c;
    const int n = idx >> 7;
    const int col = idx & 127;
    ws[col * NN + n] = fyv[c] * invY;             // FYt[a=col][n]
    ws[8192 + col * NN + n] = fxv[c] * invX;      // FXt[b=col][m]
  }
  if (tid == 0) ws[16384] = expf(sc[4]);
}

// ---------------------------------------------------------------------------
// 2048 blocks x 256 threads (4 waves) = 1 image/block, exactly 8 blocks/CU.
// R2's proven code shape (52 VGPR, SGPR filter operands, 2-way-free DS) with
// ONE change: the b-dimension is processed in 2 chunks of 64 so the T tile is
// 64 x (64+2) = 16.9 KB instead of 33.3 KB -> 8 blocks/CU fit in LDS ->
// 32 waves/CU (vs R2's 16). Out-accumulators persist in registers across
// chunks. Chunk loop is explicitly unroll-1 to avoid the R5 register blowup.
// Stage 1: wave w owns T rows 16w..16w+15; lane owns chunk column `lane`.
//          FY via s_load (wave-uniform transposed rows), Z coalesced dwords.
// Stage 2: lane owns out row n=lane; wave owns out cols 16w..16w+15.
//          T row-read at stride 66 (2-way = free), FX via s_load.
// ---------------------------------------------------------------------------
__global__ __launch_bounds__(256) void fb_filt(
    const float* __restrict__ x, const float* __restrict__ xh,
    const float* __restrict__ ws, float* __restrict__ out) {
  __shared__ __align__(16) float T[NN * TST];  // 16.9 KB

  const int tid = threadIdx.x;
  const int lane = tid & 63;
  const int w16 = __builtin_amdgcn_readfirstlane((tid >> 6) << 4);  // 16*wave
  const int img = blockIdx.x;
  const int k = img >> 1;
  const int which = img & 1;
  const float* __restrict__ Z = (which ? xh : x) + (size_t)k * (AB * AB);
  const float* __restrict__ FYt = ws;
  const float* __restrict__ FXt = ws + NN * AB;
  const float gamma = ws[2 * NN * AB];

  float acc2[16];
#pragma unroll
  for (int j = 0; j < 16; ++j) acc2[j] = 0.f;

#pragma unroll 1
  for (int c = 0; c < 2; ++c) {
    const int B0 = c << 6;

    // ---- Stage 1: T[w16+j][lane] = sum_a FYt[a][w16+j] * Z[a][B0+lane] ----
    float a1[16];
#pragma unroll
    for (int j = 0; j < 16; ++j) a1[j] = 0.f;

    const float* __restrict__ Zc = Z + B0 + lane;
#pragma unroll 4
    for (int a = 0; a < AB; ++a) {
      const float z = Zc[a << 7];                            // coalesced dword
      const float* __restrict__ fyr = FYt + (a << 6) + w16;  // uniform -> s_load
#pragma unroll
      for (int j = 0; j < 16; ++j) a1[j] = fmaf(fyr[j], z, a1[j]);
    }
#pragma unroll
    for (int j = 0; j < 16; ++j) T[(w16 + j) * TST + lane] = a1[j];  // 2-way

    __syncthreads();

    // ---- Stage 2: acc2[j] += sum_bb T[lane][bb] * FXt[B0+bb][w16+j] ----
    const float* __restrict__ Trow = &T[lane * TST];
#pragma unroll 2
    for (int bb = 0; bb < 64; bb += 2) {
      const float2 t = *(const float2*)&Trow[bb];            // 2-way = free
      const float* __restrict__ fxr = FXt + ((B0 + bb) << 6) + w16;  // s_load
      const float* __restrict__ fxr2 = fxr + NN;
#pragma unroll
      for (int j = 0; j < 16; ++j) {
        acc2[j] = fmaf(t.x, fxr[j], fmaf(t.y, fxr2[j], acc2[j]));
      }
    }

    __syncthreads();  // before next chunk overwrites T
  }

  // ---- Epilogue: out[lane][w16..w16+15], float4 stores ----
  float* orow = out + (size_t)k * 8192 + which * 4096 + lane * NN + w16;
#pragma unroll
  for (int i = 0; i < 4; ++i) {
    *(float4*)(orow + 4 * i) =
        make_float4(gamma * acc2[4 * i + 0], gamma * acc2[4 * i + 1],
                    gamma * acc2[4 * i + 2], gamma * acc2[4 * i + 3]);
  }
}

extern "C" void kernel_launch(void* const* d_in, const int* in_sizes, int n_in,
                              void* d_out, int out_size, void* d_ws, size_t ws_size,
                              hipStream_t stream) {
  const float* x = (const float*)d_in[0];
  const float* xh = (const float*)d_in[1];
  const float* h = (const float*)d_in[2];
  const float* Ww = (const float*)d_in[3];
  const float* Wb = (const float*)d_in[4];
  float* ws = (float*)d_ws;
  float* outp = (float*)d_out;

  fb_setup<<<1, 1024, 0, stream>>>(h, Ww, Wb, ws);
  fb_filt<<<2048, 256, 0, stream>>>(x, xh, ws, outp);
}